// Round 16
// baseline (872.195 us; speedup 1.0000x reference)
//
#include <hip/hip_runtime.h>

#define N_USERS 90000
#define N_ITEMS 60000
#define NN      (N_USERS + N_ITEMS)   // 150000
#define D       64
#define KDIM    128
#define NE      1600000
#define EPSF    1e-12f
#define ROWD    64                    // pk row = 64 dwords = 256B
#define TU      ((N_USERS + 63) / 64) // 1407
#define TI      ((N_ITEMS + 63) / 64) // 938
#define NINT    (TU + TI)             // 2345 intent blocks
#define GB      4096                  // persistent gnn/fused blocks

// ---------------- f16 / fp8 helpers ----------------

typedef __fp16 h2 __attribute__((ext_vector_type(2)));
typedef __fp16 h8 __attribute__((ext_vector_type(8)));
typedef float  f2 __attribute__((ext_vector_type(2)));
typedef float  f4v __attribute__((ext_vector_type(4)));

__device__ inline h2 as_h2(unsigned u) {
    union { unsigned u; h2 h; } v; v.u = u; return v.h;
}
__device__ inline h8 as_h8(uint4 u) {
    union { uint4 u; h8 h; } v; v.u = u; return v.h;
}
__device__ inline unsigned pkrtz(float a, float b) {
    auto r = __builtin_amdgcn_cvt_pkrtz(a, b);
    union { decltype(r) h; unsigned u; } v; v.h = r; return v.u;
}
__device__ inline f2 dec8lo(unsigned u) {
    return __builtin_amdgcn_cvt_pk_f32_fp8((int)u, false);
}
__device__ inline f2 dec8hi(unsigned u) {
    return __builtin_amdgcn_cvt_pk_f32_fp8((int)u, true);
}
__device__ inline unsigned enc8(float a, float b, float c, float d) {
    int u = __builtin_amdgcn_cvt_pk_fp8_f32(a, b, 0, false);
    u = __builtin_amdgcn_cvt_pk_fp8_f32(c, d, u, true);
    return (unsigned)u;
}

// ---------------- pre-pass: deg || init || W-fragments ------------

#define EB   ((NE + 255) / 256)         // 6250
#define IB   ((NN * 16 + 255) / 256)    // 9375
#define PREG (EB + IB + 16)

__global__ void k_pre(const int* __restrict__ h, int* __restrict__ deg,
                      const float* __restrict__ emb,
                      float* __restrict__ acc, unsigned* __restrict__ pkA,
                      const float* __restrict__ Wu, const float* __restrict__ Wi,
                      uint4* __restrict__ WfA, uint4* __restrict__ Wf2) {
    int bid = blockIdx.x;
    if (bid < EB) {
        int e = bid * 256 + threadIdx.x;
        if (e < NE) atomicAdd(&deg[h[e]], 1);
    } else if (bid < EB + IB) {
        int i = (bid - EB) * 256 + threadIdx.x;
        if (i >= NN * 16) return;
        f4v v = __builtin_nontemporal_load((const f4v*)emb + i);
        __builtin_nontemporal_store(v, (f4v*)acc + i);
        int row = i >> 4, l = i & 15;
        *(uint2*)&pkA[(size_t)row * ROWD + 32 + 2 * l] =
            make_uint2(pkrtz(v.x, v.y), pkrtz(v.z, v.w));
    } else {
        int i = (bid - EB - IB) * 256 + threadIdx.x;
        if (i >= 4096) return;
        int ph  = i >> 11;             // 0: phase1 frags, 1: phase2 frags
        int r   = i & 2047;
        int mat = r >> 10;
        int rr  = r & 1023;
        const float* W = mat ? Wi : Wu;
        union { __fp16 hh[8]; uint4 u; } pkt;
        if (!ph) {
            int nt = rr >> 7, ks = (rr >> 6) & 1, lane = rr & 63;
            int q = lane >> 4, c = lane & 15;
            #pragma unroll
            for (int j = 0; j < 8; ++j)
                pkt.hh[j] = (__fp16)W[(32 * ks + 8 * q + j) * KDIM + nt * 16 + c];
            WfA[((mat * 8 + nt) * 2 + ks) * 64 + lane] = pkt.u;
        } else {
            int nt = rr >> 8, ks = (rr >> 6) & 3, lane = rr & 63;
            int q = lane >> 4, c = lane & 15;
            #pragma unroll
            for (int j = 0; j < 8; ++j)
                pkt.hh[j] = (__fp16)W[(nt * 16 + c) * KDIM + 32 * ks + 8 * q + j];
            Wf2[((mat * 4 + nt) * 4 + ks) * 64 + lane] = pkt.u;
        }
    }
}

__global__ void k_rowoff(const int* __restrict__ deg, int* __restrict__ counter,
                         int* __restrict__ row_off, int2* __restrict__ rodeg,
                         float* __restrict__ d_inv) {
    int i = blockIdx.x * blockDim.x + threadIdx.x;
    if (i >= NN) return;
    int d = deg[i];
    int ro = atomicAdd(counter, d);
    row_off[i] = ro;
    rodeg[i]   = make_int2(ro, d);
    d_inv[i]   = (d > 0) ? rsqrtf((float)d) : 0.f;
}

__global__ void k_scatter(const int* __restrict__ h, const int* __restrict__ t,
                          const int* __restrict__ row_off, int* __restrict__ row_cur,
                          const float* __restrict__ d_inv,
                          int2* __restrict__ csr) {
    int e = blockIdx.x * blockDim.x + threadIdx.x;
    if (e >= NE) return;
    int hh = h[e], tt = t[e];
    int slot = row_off[hh] + atomicAdd(&row_cur[hh], 1);
    csr[slot] = make_int2(tt, __float_as_int(d_inv[hh] * d_inv[tt]));
}

// ---------------- k_mid: intent (MFMA) blocks + persistent gnn blocks --------
// pk row (64 dwords): [2i]=ghat fp8x4 dims 4i..4i+3, [2i+1]=ihat fp8x4,
//                     [32+2i,33+2i]=x f16 dims 4i..4i+3
__global__ __launch_bounds__(256) void k_mid(const int2* __restrict__ rodeg,
                                             const int2* __restrict__ csr,
                                             unsigned* __restrict__ pk,
                                             unsigned* __restrict__ intl_h,
                                             const uint4* __restrict__ WfA,
                                             const uint4* __restrict__ Wf2,
                                             float* __restrict__ base_) {
    __shared__ unsigned Plds[4096];    // P matrix [64][128] f16, XOR-swizzled
    int tid = threadIdx.x;
    int bid = blockIdx.x;

    if (bid < NINT) {
        // ================= intent path (MFMA f16) =================
        int mat, bse, count, n0;
        if (bid < TU) { mat = 0; bse = 0;       count = N_USERS; n0 = bid * 64; }
        else          { mat = 1; bse = N_USERS; count = N_ITEMS; n0 = (bid - TU) * 64; }

        int wv = tid >> 6, la = tid & 63;
        int q = la >> 4, c = la & 15;

        int nA = n0 + wv * 16 + c;
        size_t gA = (size_t)min(bse + nA, NN - 1);
        const unsigned* prA = pk + gA * ROWD;
        uint4 a0u = *(const uint4*)&prA[32 + 4 * q];
        uint4 a1u = *(const uint4*)&prA[48 + 4 * q];

        // phase 1: S = X @ W   (M=64 N=128 K=64)
        f4v S[8];
        #pragma unroll
        for (int nt = 0; nt < 8; ++nt) S[nt] = (f4v){0.f, 0.f, 0.f, 0.f};
        const uint4* WA = WfA + (size_t)mat * 1024;
        #pragma unroll
        for (int nt = 0; nt < 8; ++nt) {
            h8 B0 = as_h8(WA[(nt * 2 + 0) * 64 + la]);
            h8 B1 = as_h8(WA[(nt * 2 + 1) * 64 + la]);
            S[nt] = __builtin_amdgcn_mfma_f32_16x16x32_f16(as_h8(a0u), B0, S[nt], 0, 0, 0);
            S[nt] = __builtin_amdgcn_mfma_f32_16x16x32_f16(as_h8(a1u), B1, S[nt], 0, 0, 0);
        }

        float inv_s[4];
        #pragma unroll
        for (int reg = 0; reg < 4; ++reg) {
            float m = S[0][reg];
            #pragma unroll
            for (int nt = 1; nt < 8; ++nt) m = fmaxf(m, S[nt][reg]);
            m = fmaxf(m, __shfl_xor(m, 1)); m = fmaxf(m, __shfl_xor(m, 2));
            m = fmaxf(m, __shfl_xor(m, 4)); m = fmaxf(m, __shfl_xor(m, 8));
            float sm = 0.f;
            #pragma unroll
            for (int nt = 0; nt < 8; ++nt) {
                float e_ = __expf(S[nt][reg] - m);
                S[nt][reg] = e_;
                sm += e_;
            }
            sm += __shfl_xor(sm, 1); sm += __shfl_xor(sm, 2);
            sm += __shfl_xor(sm, 4); sm += __shfl_xor(sm, 8);
            inv_s[reg] = 1.f / sm;
        }

        #pragma unroll
        for (int reg = 0; reg < 4; ++reg) {
            int ln = wv * 16 + q * 4 + reg;
            #pragma unroll
            for (int nt = 0; nt < 8; ++nt) {
                float v  = S[nt][reg] * inv_s[reg];
                float v1 = __shfl_xor(v, 1);
                if (!(c & 1)) {
                    int byte_in_row = nt * 32 + c * 2;
                    int sw = byte_in_row ^ ((ln & 7) << 4);
                    *(unsigned*)((char*)Plds + ln * 256 + sw) = pkrtz(v, v1);
                }
            }
        }

        // phase 2: intl = P @ W^T  (M=64 N=64 K=128)
        f4v O[4];
        #pragma unroll
        for (int nt = 0; nt < 4; ++nt) O[nt] = (f4v){0.f, 0.f, 0.f, 0.f};
        const uint4* W2 = Wf2 + (size_t)mat * 1024;
        int lnA = wv * 16 + c;
        #pragma unroll
        for (int ks = 0; ks < 4; ++ks) {
            int byte_in_row = (32 * ks + 8 * q) * 2;
            int sw = byte_in_row ^ ((lnA & 7) << 4);
            uint4 au = *(const uint4*)((char*)Plds + lnA * 256 + sw);
            #pragma unroll
            for (int nt = 0; nt < 4; ++nt) {
                h8 Bp = as_h8(W2[(nt * 4 + ks) * 64 + la]);
                O[nt] = __builtin_amdgcn_mfma_f32_16x16x32_f16(as_h8(au), Bp, O[nt], 0, 0, 0);
            }
        }

        #pragma unroll
        for (int reg = 0; reg < 4; ++reg) {
            float ss = 0.f;
            #pragma unroll
            for (int nt = 0; nt < 4; ++nt) ss = fmaf(O[nt][reg], O[nt][reg], ss);
            ss += __shfl_xor(ss, 1); ss += __shfl_xor(ss, 2);
            ss += __shfl_xor(ss, 4); ss += __shfl_xor(ss, 8);
            float invn = 1.f / fmaxf(sqrtf(ss), EPSF);
            int n = n0 + wv * 16 + q * 4 + reg;
            bool valid = n < count;
            size_t g = (size_t)(bse + n);
            #pragma unroll
            for (int nt = 0; nt < 4; ++nt) {
                float v  = O[nt][reg];
                float v1 = __shfl_xor(v, 1);
                float v2 = __shfl_xor(v, 2);
                float v3 = __shfl_xor(v, 3);
                if (valid) {
                    if (!(c & 1))
                        __builtin_nontemporal_store(pkrtz(v, v1),
                            &intl_h[g * 32 + ((nt * 16 + c) >> 1)]);
                    if (!(c & 3))
                        pk[g * ROWD + 2 * ((nt * 16 + c) >> 2) + 1] =
                            enc8(v * invn, v1 * invn, v2 * invn, v3 * invn);
                }
            }
        }
    } else {
        // ===== gnn path: persistent waves, 8x8 groups, 2-stage pipeline =======
        int lane = tid & 63;
        int grp = lane >> 3, l8 = lane & 7;   // lane owns dims 8*l8 .. 8*l8+7
        int nw = GB * 4;
        for (int wid = (bid - NINT) * 4 + (tid >> 6); wid < NN; wid += nw) {
            int2 rd = rodeg[wid];
            int s = rd.x, eend = rd.x + rd.y;
            float a0 = 0.f, a1 = 0.f, a2 = 0.f, a3 = 0.f;
            float a4 = 0.f, a5 = 0.f, a6 = 0.f, a7 = 0.f;
            int e = s;
            int2 c  = csr[min(s + grp, eend - 1)];
            uint4 w = *(const uint4*)&pk[(size_t)c.x * ROWD + 32 + 4 * l8];
            int2 c1 = csr[min(s + 8 + grp, eend - 1)];
            for (; e + 7 < eend; e += 8) {
                int2 c2  = csr[min(e + 16 + grp, eend - 1)];
                uint4 w1 = *(const uint4*)&pk[(size_t)c1.x * ROWD + 32 + 4 * l8];
                float gv = __int_as_float(c.y);
                h2 x0 = as_h2(w.x), x1 = as_h2(w.y), x2 = as_h2(w.z), x3 = as_h2(w.w);
                a0 = fmaf(gv, (float)x0.x, a0); a1 = fmaf(gv, (float)x0.y, a1);
                a2 = fmaf(gv, (float)x1.x, a2); a3 = fmaf(gv, (float)x1.y, a3);
                a4 = fmaf(gv, (float)x2.x, a4); a5 = fmaf(gv, (float)x2.y, a5);
                a6 = fmaf(gv, (float)x3.x, a6); a7 = fmaf(gv, (float)x3.y, a7);
                c = c1; c1 = c2; w = w1;
            }
            if (e < eend) {
                bool val = e + grp < eend;
                float gv = val ? __int_as_float(c.y) : 0.f;
                h2 x0 = as_h2(w.x), x1 = as_h2(w.y), x2 = as_h2(w.z), x3 = as_h2(w.w);
                a0 = fmaf(gv, (float)x0.x, a0); a1 = fmaf(gv, (float)x0.y, a1);
                a2 = fmaf(gv, (float)x1.x, a2); a3 = fmaf(gv, (float)x1.y, a3);
                a4 = fmaf(gv, (float)x2.x, a4); a5 = fmaf(gv, (float)x2.y, a5);
                a6 = fmaf(gv, (float)x3.x, a6); a7 = fmaf(gv, (float)x3.y, a7);
            }
            #pragma unroll
            for (int m = 8; m <= 32; m <<= 1) {
                a0 += __shfl_xor(a0, m); a1 += __shfl_xor(a1, m);
                a2 += __shfl_xor(a2, m); a3 += __shfl_xor(a3, m);
                a4 += __shfl_xor(a4, m); a5 += __shfl_xor(a5, m);
                a6 += __shfl_xor(a6, m); a7 += __shfl_xor(a7, m);
            }
            float ss = fmaf(a0, a0, fmaf(a1, a1, fmaf(a2, a2, a3 * a3)))
                     + fmaf(a4, a4, fmaf(a5, a5, fmaf(a6, a6, a7 * a7)));
            ss += __shfl_xor(ss, 1); ss += __shfl_xor(ss, 2); ss += __shfl_xor(ss, 4);
            float inv = 1.f / fmaxf(sqrtf(ss), EPSF);
            if (grp == 0) {
                unsigned* pr = pk + (size_t)wid * ROWD;
                pr[4 * l8]     = enc8(a0 * inv, a1 * inv, a2 * inv, a3 * inv);
                pr[4 * l8 + 2] = enc8(a4 * inv, a5 * inv, a6 * inv, a7 * inv);
                uint4 xw = *(const uint4*)&pr[32 + 4 * l8];
                h2 x0 = as_h2(xw.x), x1 = as_h2(xw.y), x2 = as_h2(xw.z), x3 = as_h2(xw.w);
                f4v* bp = (f4v*)base_ + (size_t)wid * 16 + 2 * l8;
                f4v b0, b1;
                b0.x = a0 + (float)x0.x; b0.y = a1 + (float)x0.y;
                b0.z = a2 + (float)x1.x; b0.w = a3 + (float)x1.y;
                b1.x = a4 + (float)x2.x; b1.y = a5 + (float)x2.y;
                b1.z = a6 + (float)x3.x; b1.w = a7 + (float)x3.y;
                __builtin_nontemporal_store(b0, bp);
                __builtin_nontemporal_store(b1, bp + 1);
            }
        }
    }
}

// ---------------- k_fused: persistent waves; 2-stage pipelined edge loop -----
// wave = 4 groups x 16 lanes; group g handles edges e+g / e+4+g
__global__ __launch_bounds__(256) void k_fused(const int2* __restrict__ rodeg,
                                               const int2* __restrict__ csr,
                                               const unsigned* __restrict__ pk,
                                               const unsigned* __restrict__ intl_h,
                                               const float* __restrict__ base_,
                                               unsigned* __restrict__ pknext,
                                               float* __restrict__ acc) {
    int lane = threadIdx.x & 63;
    int grp = lane >> 4, l16 = lane & 15;
    int nw = GB * 4;
    for (int wid = blockIdx.x * 4 + (threadIdx.x >> 6); wid < NN; wid += nw) {
        const unsigned* ph = pk + (size_t)wid * ROWD;
        uint2 hq = *(const uint2*)&ph[2 * l16];
        f2 hgl = dec8lo(hq.x), hgh = dec8hi(hq.x);
        f2 hil = dec8lo(hq.y), hih = dec8hi(hq.y);

        int2 rd = rodeg[wid];
        int s = rd.x, eend = rd.x + rd.y;
        float sg = 0.f, si = 0.f;
        float g0 = 0.f, g1 = 0.f, g2 = 0.f, g3 = 0.f;
        float i0 = 0.f, i1 = 0.f, i2 = 0.f, i3 = 0.f;

        int e = s;
        int tA = csr[min(s + grp, eend - 1)].x;
        int tB = csr[min(s + 4 + grp, eend - 1)].x;
        const unsigned* pA = pk + (size_t)tA * ROWD;
        const unsigned* pB = pk + (size_t)tB * ROWD;
        uint2 qA = *(const uint2*)&pA[2 * l16];
        uint2 wA = *(const uint2*)&pA[32 + 2 * l16];
        uint2 qB = *(const uint2*)&pB[2 * l16];
        uint2 wB = *(const uint2*)&pB[32 + 2 * l16];
        int tA1 = csr[min(s + 8 + grp, eend - 1)].x;
        int tB1 = csr[min(s + 12 + grp, eend - 1)].x;

        for (; e + 7 < eend; e += 8) {
            int tA2 = csr[min(e + 16 + grp, eend - 1)].x;
            int tB2 = csr[min(e + 20 + grp, eend - 1)].x;
            const unsigned* pA1 = pk + (size_t)tA1 * ROWD;
            const unsigned* pB1 = pk + (size_t)tB1 * ROWD;
            uint2 qA1 = *(const uint2*)&pA1[2 * l16];
            uint2 wA1 = *(const uint2*)&pA1[32 + 2 * l16];
            uint2 qB1 = *(const uint2*)&pB1[2 * l16];
            uint2 wB1 = *(const uint2*)&pB1[32 + 2 * l16];
            f2 gA01 = dec8lo(qA.x), gA23 = dec8hi(qA.x);
            f2 iA01 = dec8lo(qA.y), iA23 = dec8hi(qA.y);
            f2 gB01 = dec8lo(qB.x), gB23 = dec8hi(qB.x);
            f2 iB01 = dec8lo(qB.y), iB23 = dec8hi(qB.y);
            float pgA = fmaf(hgl.x, gA01.x, fmaf(hgl.y, gA01.y,
                        fmaf(hgh.x, gA23.x, hgh.y * gA23.y)));
            float piA = fmaf(hil.x, iA01.x, fmaf(hil.y, iA01.y,
                        fmaf(hih.x, iA23.x, hih.y * iA23.y)));
            float pgB = fmaf(hgl.x, gB01.x, fmaf(hgl.y, gB01.y,
                        fmaf(hgh.x, gB23.x, hgh.y * gB23.y)));
            float piB = fmaf(hil.x, iB01.x, fmaf(hil.y, iB01.y,
                        fmaf(hih.x, iB23.x, hih.y * iB23.y)));
            #pragma unroll
            for (int m = 1; m <= 8; m <<= 1) {
                pgA += __shfl_xor(pgA, m); piA += __shfl_xor(piA, m);
                pgB += __shfl_xor(pgB, m); piB += __shfl_xor(piB, m);
            }
            float agA = fmaf(pgA, 0.5f, 0.5f), aiA = fmaf(piA, 0.5f, 0.5f);
            float agB = fmaf(pgB, 0.5f, 0.5f), aiB = fmaf(piB, 0.5f, 0.5f);
            sg += agA + agB; si += aiA + aiB;
            h2 xa0 = as_h2(wA.x), xa1 = as_h2(wA.y);
            h2 xb0 = as_h2(wB.x), xb1 = as_h2(wB.y);
            g0 = fmaf(agA, (float)xa0.x, g0); g1 = fmaf(agA, (float)xa0.y, g1);
            g2 = fmaf(agA, (float)xa1.x, g2); g3 = fmaf(agA, (float)xa1.y, g3);
            i0 = fmaf(aiA, (float)xa0.x, i0); i1 = fmaf(aiA, (float)xa0.y, i1);
            i2 = fmaf(aiA, (float)xa1.x, i2); i3 = fmaf(aiA, (float)xa1.y, i3);
            g0 = fmaf(agB, (float)xb0.x, g0); g1 = fmaf(agB, (float)xb0.y, g1);
            g2 = fmaf(agB, (float)xb1.x, g2); g3 = fmaf(agB, (float)xb1.y, g3);
            i0 = fmaf(aiB, (float)xb0.x, i0); i1 = fmaf(aiB, (float)xb0.y, i1);
            i2 = fmaf(aiB, (float)xb1.x, i2); i3 = fmaf(aiB, (float)xb1.y, i3);
            tA1 = tA2; tB1 = tB2;
            qA = qA1; wA = wA1; qB = qB1; wB = wB1;
        }
        if (e < eend) {
            bool val = e + grp < eend;
            f2 tg01 = dec8lo(qA.x), tg23 = dec8hi(qA.x);
            f2 ti01 = dec8lo(qA.y), ti23 = dec8hi(qA.y);
            float pg = fmaf(hgl.x, tg01.x, fmaf(hgl.y, tg01.y,
                       fmaf(hgh.x, tg23.x, hgh.y * tg23.y)));
            float pi = fmaf(hil.x, ti01.x, fmaf(hil.y, ti01.y,
                       fmaf(hih.x, ti23.x, hih.y * ti23.y)));
            #pragma unroll
            for (int m = 1; m <= 8; m <<= 1) {
                pg += __shfl_xor(pg, m); pi += __shfl_xor(pi, m);
            }
            float ag = fmaf(pg, 0.5f, 0.5f), ai = fmaf(pi, 0.5f, 0.5f);
            if (!val) { ag = 0.f; ai = 0.f; }
            sg += ag; si += ai;
            h2 x0 = as_h2(wA.x), x1 = as_h2(wA.y);
            g0 = fmaf(ag, (float)x0.x, g0); g1 = fmaf(ag, (float)x0.y, g1);
            g2 = fmaf(ag, (float)x1.x, g2); g3 = fmaf(ag, (float)x1.y, g3);
            i0 = fmaf(ai, (float)x0.x, i0); i1 = fmaf(ai, (float)x0.y, i1);
            i2 = fmaf(ai, (float)x1.x, i2); i3 = fmaf(ai, (float)x1.y, i3);
        }
        if (e + 4 < eend) {
            bool val = e + 4 + grp < eend;
            f2 tg01 = dec8lo(qB.x), tg23 = dec8hi(qB.x);
            f2 ti01 = dec8lo(qB.y), ti23 = dec8hi(qB.y);
            float pg = fmaf(hgl.x, tg01.x, fmaf(hgl.y, tg01.y,
                       fmaf(hgh.x, tg23.x, hgh.y * tg23.y)));
            float pi = fmaf(hil.x, ti01.x, fmaf(hil.y, ti01.y,
                       fmaf(hih.x, ti23.x, hih.y * ti23.y)));
            #pragma unroll
            for (int m = 1; m <= 8; m <<= 1) {
                pg += __shfl_xor(pg, m); pi += __shfl_xor(pi, m);
            }
            float ag = fmaf(pg, 0.5f, 0.5f), ai = fmaf(pi, 0.5f, 0.5f);
            if (!val) { ag = 0.f; ai = 0.f; }
            sg += ag; si += ai;
            h2 x0 = as_h2(wB.x), x1 = as_h2(wB.y);
            g0 = fmaf(ag, (float)x0.x, g0); g1 = fmaf(ag, (float)x0.y, g1);
            g2 = fmaf(ag, (float)x1.x, g2); g3 = fmaf(ag, (float)x1.y, g3);
            i0 = fmaf(ai, (float)x0.x, i0); i1 = fmaf(ai, (float)x0.y, i1);
            i2 = fmaf(ai, (float)x1.x, i2); i3 = fmaf(ai, (float)x1.y, i3);
        }

        #pragma unroll
        for (int m = 16; m <= 32; m <<= 1) {
            sg += __shfl_xor(sg, m); si += __shfl_xor(si, m);
            g0 += __shfl_xor(g0, m); g1 += __shfl_xor(g1, m);
            g2 += __shfl_xor(g2, m); g3 += __shfl_xor(g3, m);
            i0 += __shfl_xor(i0, m); i1 += __shfl_xor(i1, m);
            i2 += __shfl_xor(i2, m); i3 += __shfl_xor(i3, m);
        }

        if (grp == 0) {
            float invg = sg > 0.f ? 1.f / sg : 0.f;
            float invi = si > 0.f ? 1.f / si : 0.f;
            size_t bidx = (size_t)wid * 16 + l16;
            f4v b = __builtin_nontemporal_load((const f4v*)base_ + bidx);
            uint2 iw;
            iw.x = __builtin_nontemporal_load(&intl_h[(size_t)wid * 32 + 2 * l16]);
            iw.y = __builtin_nontemporal_load(&intl_h[(size_t)wid * 32 + 2 * l16 + 1]);
            h2 il0 = as_h2(iw.x), il1 = as_h2(iw.y);
            float o0 = b.x + (float)il0.x + invg * g0 + invi * i0;
            float o1 = b.y + (float)il0.y + invg * g1 + invi * i1;
            float o2 = b.z + (float)il1.x + invg * g2 + invi * i2;
            float o3 = b.w + (float)il1.y + invg * g3 + invi * i3;
            *(uint2*)&pknext[(size_t)wid * ROWD + 32 + 2 * l16] =
                make_uint2(pkrtz(o0, o1), pkrtz(o2, o3));
            f4v a = __builtin_nontemporal_load((const f4v*)acc + bidx);
            a.x += o0; a.y += o1; a.z += o2; a.w += o3;
            __builtin_nontemporal_store(a, (f4v*)acc + bidx);
        }
    }
}

// ---------------- launch ----------------

extern "C" void kernel_launch(void* const* d_in, const int* in_sizes, int n_in,
                              void* d_out, int out_size, void* d_ws, size_t ws_size,
                              hipStream_t stream) {
    const float* emb   = (const float*)d_in[0];
    const float* Wu    = (const float*)d_in[1];
    const float* Wi    = (const float*)d_in[2];
    const int*   all_h = (const int*)d_in[3];
    const int*   all_t = (const int*)d_in[4];
    float*       acc   = (float*)d_out;

    char*  bp  = (char*)d_ws;
    size_t off = 0;
    auto take = [&](size_t bytes) -> char* {
        char* r = bp + off;
        off = (off + bytes + 255) & ~(size_t)255;
        return r;
    };
    int*      deg     = (int*)     take((size_t)NN * 4);
    int*      row_off = (int*)     take((size_t)NN * 4);
    int2*     rodeg   = (int2*)    take((size_t)NN * 8);
    int*      row_cur = (int*)     take((size_t)NN * 4);
    int*      counter = (int*)     take(256);
    float*    d_inv   = (float*)   take((size_t)NN * 4);
    int2*     csr     = (int2*)    take((size_t)NE * 8);
    unsigned* pkA     = (unsigned*)take((size_t)NN * ROWD * 4);
    unsigned* pkB     = (unsigned*)take((size_t)NN * ROWD * 4);
    unsigned* intl_h  = (unsigned*)take((size_t)NN * 32 * 4);
    float*    base_   = (float*)   take((size_t)NN * D * 4);
    uint4*    WfA     = (uint4*)   take((size_t)2048 * 16);
    uint4*    Wf2     = (uint4*)   take((size_t)2048 * 16);
    (void)ws_size; (void)in_sizes; (void)n_in; (void)out_size;

    hipMemsetAsync(deg, 0, (size_t)NN * 4, stream);
    hipMemsetAsync(row_cur, 0, (size_t)NN * 4, stream);
    hipMemsetAsync(counter, 0, 256, stream);

    const int NBK = (NN + 255) / 256;
    k_pre<<<PREG, 256, 0, stream>>>(all_h, deg, emb, acc, pkA, Wu, Wi, WfA, Wf2);
    k_rowoff<<<NBK, 256, 0, stream>>>(deg, counter, row_off, rodeg, d_inv);
    k_scatter<<<EB, 256, 0, stream>>>(all_h, all_t, row_off, row_cur, d_inv, csr);

    unsigned* cur = pkA;
    unsigned* nxt = pkB;
    for (int l = 0; l < 3; ++l) {
        k_mid<<<NINT + GB, 256, 0, stream>>>(rodeg, csr, cur, intl_h,
                                             WfA, Wf2, base_);
        k_fused<<<GB, 256, 0, stream>>>(rodeg, csr, cur, intl_h,
                                        base_, nxt, acc);
        unsigned* tmp = cur; cur = nxt; nxt = tmp;
    }
}

// Round 17
// 784.284 us; speedup vs baseline: 1.1121x; 1.1121x over previous
//
#include <hip/hip_runtime.h>

#define N_USERS 90000
#define N_ITEMS 60000
#define NN      (N_USERS + N_ITEMS)   // 150000
#define D       64
#define KDIM    128
#define NE      1600000
#define EPSF    1e-12f
#define ROWD    64                    // pk row = 64 dwords = 256B
#define TU      ((N_USERS + 63) / 64) // 1407
#define TI      ((N_ITEMS + 63) / 64) // 938
#define NINT    (TU + TI)             // 2345 intent blocks
#define GB      4096                  // persistent gnn/fused blocks

// ---------------- f16 / fp8 helpers ----------------

typedef __fp16 h2 __attribute__((ext_vector_type(2)));
typedef __fp16 h8 __attribute__((ext_vector_type(8)));
typedef float  f2 __attribute__((ext_vector_type(2)));
typedef float  f4v __attribute__((ext_vector_type(4)));

__device__ inline h2 as_h2(unsigned u) {
    union { unsigned u; h2 h; } v; v.u = u; return v.h;
}
__device__ inline h8 as_h8(uint4 u) {
    union { uint4 u; h8 h; } v; v.u = u; return v.h;
}
__device__ inline unsigned pkrtz(float a, float b) {
    auto r = __builtin_amdgcn_cvt_pkrtz(a, b);
    union { decltype(r) h; unsigned u; } v; v.h = r; return v.u;
}
__device__ inline f2 dec8lo(unsigned u) {
    return __builtin_amdgcn_cvt_pk_f32_fp8((int)u, false);
}
__device__ inline f2 dec8hi(unsigned u) {
    return __builtin_amdgcn_cvt_pk_f32_fp8((int)u, true);
}
__device__ inline unsigned enc8(float a, float b, float c, float d) {
    int u = __builtin_amdgcn_cvt_pk_fp8_f32(a, b, 0, false);
    u = __builtin_amdgcn_cvt_pk_fp8_f32(c, d, u, true);
    return (unsigned)u;
}

// ---------------- pre-pass: deg || init || W-fragments ------------

#define EB   ((NE + 255) / 256)         // 6250
#define IB   ((NN * 16 + 255) / 256)    // 9375
#define PREG (EB + IB + 16)

__global__ void k_pre(const int* __restrict__ h, int* __restrict__ deg,
                      const float* __restrict__ emb,
                      float* __restrict__ acc, unsigned* __restrict__ pkA,
                      const float* __restrict__ Wu, const float* __restrict__ Wi,
                      uint4* __restrict__ WfA, uint4* __restrict__ Wf2) {
    int bid = blockIdx.x;
    if (bid < EB) {
        int e = bid * 256 + threadIdx.x;
        if (e < NE) atomicAdd(&deg[h[e]], 1);
    } else if (bid < EB + IB) {
        int i = (bid - EB) * 256 + threadIdx.x;
        if (i >= NN * 16) return;
        float4 v = ((const float4*)emb)[i];
        ((float4*)acc)[i] = v;
        int row = i >> 4, l = i & 15;
        *(uint2*)&pkA[(size_t)row * ROWD + 32 + 2 * l] =
            make_uint2(pkrtz(v.x, v.y), pkrtz(v.z, v.w));
    } else {
        int i = (bid - EB - IB) * 256 + threadIdx.x;
        if (i >= 4096) return;
        int ph  = i >> 11;             // 0: phase1 frags, 1: phase2 frags
        int r   = i & 2047;
        int mat = r >> 10;
        int rr  = r & 1023;
        const float* W = mat ? Wi : Wu;
        union { __fp16 hh[8]; uint4 u; } pkt;
        if (!ph) {
            int nt = rr >> 7, ks = (rr >> 6) & 1, lane = rr & 63;
            int q = lane >> 4, c = lane & 15;
            #pragma unroll
            for (int j = 0; j < 8; ++j)
                pkt.hh[j] = (__fp16)W[(32 * ks + 8 * q + j) * KDIM + nt * 16 + c];
            WfA[((mat * 8 + nt) * 2 + ks) * 64 + lane] = pkt.u;
        } else {
            int nt = rr >> 8, ks = (rr >> 6) & 3, lane = rr & 63;
            int q = lane >> 4, c = lane & 15;
            #pragma unroll
            for (int j = 0; j < 8; ++j)
                pkt.hh[j] = (__fp16)W[(nt * 16 + c) * KDIM + 32 * ks + 8 * q + j];
            Wf2[((mat * 4 + nt) * 4 + ks) * 64 + lane] = pkt.u;
        }
    }
}

__global__ void k_rowoff(const int* __restrict__ deg, int* __restrict__ counter,
                         int* __restrict__ row_off, int2* __restrict__ rodeg,
                         float* __restrict__ d_inv) {
    int i = blockIdx.x * blockDim.x + threadIdx.x;
    if (i >= NN) return;
    int d = deg[i];
    int ro = atomicAdd(counter, d);
    row_off[i] = ro;
    rodeg[i]   = make_int2(ro, d);
    d_inv[i]   = (d > 0) ? rsqrtf((float)d) : 0.f;
}

__global__ void k_scatter(const int* __restrict__ h, const int* __restrict__ t,
                          const int* __restrict__ row_off, int* __restrict__ row_cur,
                          const float* __restrict__ d_inv,
                          int2* __restrict__ csr) {
    int e = blockIdx.x * blockDim.x + threadIdx.x;
    if (e >= NE) return;
    int hh = h[e], tt = t[e];
    int slot = row_off[hh] + atomicAdd(&row_cur[hh], 1);
    csr[slot] = make_int2(tt, __float_as_int(d_inv[hh] * d_inv[tt]));
}

// ---------------- k_mid: intent (MFMA) blocks + persistent gnn blocks --------
// pk row (64 dwords): [2i]=ghat fp8x4 dims 4i..4i+3, [2i+1]=ihat fp8x4,
//                     [32+2i,33+2i]=x f16 dims 4i..4i+3
// base16 row (32 dwords): gnn+x in f16 pairs
__global__ __launch_bounds__(256) void k_mid(const int2* __restrict__ rodeg,
                                             const int2* __restrict__ csr,
                                             unsigned* __restrict__ pk,
                                             unsigned* __restrict__ intl_h,
                                             const uint4* __restrict__ WfA,
                                             const uint4* __restrict__ Wf2,
                                             unsigned* __restrict__ base16) {
    __shared__ unsigned Plds[4096];    // P matrix [64][128] f16, XOR-swizzled
    int tid = threadIdx.x;
    int bid = blockIdx.x;

    if (bid < NINT) {
        // ================= intent path (MFMA f16) =================
        int mat, bse, count, n0;
        if (bid < TU) { mat = 0; bse = 0;       count = N_USERS; n0 = bid * 64; }
        else          { mat = 1; bse = N_USERS; count = N_ITEMS; n0 = (bid - TU) * 64; }

        int wv = tid >> 6, la = tid & 63;
        int q = la >> 4, c = la & 15;

        int nA = n0 + wv * 16 + c;
        size_t gA = (size_t)min(bse + nA, NN - 1);
        const unsigned* prA = pk + gA * ROWD;
        uint4 a0u = *(const uint4*)&prA[32 + 4 * q];
        uint4 a1u = *(const uint4*)&prA[48 + 4 * q];

        // phase 1: S = X @ W   (M=64 N=128 K=64)
        f4v S[8];
        #pragma unroll
        for (int nt = 0; nt < 8; ++nt) S[nt] = (f4v){0.f, 0.f, 0.f, 0.f};
        const uint4* WA = WfA + (size_t)mat * 1024;
        #pragma unroll
        for (int nt = 0; nt < 8; ++nt) {
            h8 B0 = as_h8(WA[(nt * 2 + 0) * 64 + la]);
            h8 B1 = as_h8(WA[(nt * 2 + 1) * 64 + la]);
            S[nt] = __builtin_amdgcn_mfma_f32_16x16x32_f16(as_h8(a0u), B0, S[nt], 0, 0, 0);
            S[nt] = __builtin_amdgcn_mfma_f32_16x16x32_f16(as_h8(a1u), B1, S[nt], 0, 0, 0);
        }

        float inv_s[4];
        #pragma unroll
        for (int reg = 0; reg < 4; ++reg) {
            float m = S[0][reg];
            #pragma unroll
            for (int nt = 1; nt < 8; ++nt) m = fmaxf(m, S[nt][reg]);
            m = fmaxf(m, __shfl_xor(m, 1)); m = fmaxf(m, __shfl_xor(m, 2));
            m = fmaxf(m, __shfl_xor(m, 4)); m = fmaxf(m, __shfl_xor(m, 8));
            float sm = 0.f;
            #pragma unroll
            for (int nt = 0; nt < 8; ++nt) {
                float e_ = __expf(S[nt][reg] - m);
                S[nt][reg] = e_;
                sm += e_;
            }
            sm += __shfl_xor(sm, 1); sm += __shfl_xor(sm, 2);
            sm += __shfl_xor(sm, 4); sm += __shfl_xor(sm, 8);
            inv_s[reg] = 1.f / sm;
        }

        #pragma unroll
        for (int reg = 0; reg < 4; ++reg) {
            int ln = wv * 16 + q * 4 + reg;
            #pragma unroll
            for (int nt = 0; nt < 8; ++nt) {
                float v  = S[nt][reg] * inv_s[reg];
                float v1 = __shfl_xor(v, 1);
                if (!(c & 1)) {
                    int byte_in_row = nt * 32 + c * 2;
                    int sw = byte_in_row ^ ((ln & 7) << 4);
                    *(unsigned*)((char*)Plds + ln * 256 + sw) = pkrtz(v, v1);
                }
            }
        }

        // phase 2: intl = P @ W^T  (M=64 N=64 K=128)
        f4v O[4];
        #pragma unroll
        for (int nt = 0; nt < 4; ++nt) O[nt] = (f4v){0.f, 0.f, 0.f, 0.f};
        const uint4* W2 = Wf2 + (size_t)mat * 1024;
        int lnA = wv * 16 + c;
        #pragma unroll
        for (int ks = 0; ks < 4; ++ks) {
            int byte_in_row = (32 * ks + 8 * q) * 2;
            int sw = byte_in_row ^ ((lnA & 7) << 4);
            uint4 au = *(const uint4*)((char*)Plds + lnA * 256 + sw);
            #pragma unroll
            for (int nt = 0; nt < 4; ++nt) {
                h8 Bp = as_h8(W2[(nt * 4 + ks) * 64 + la]);
                O[nt] = __builtin_amdgcn_mfma_f32_16x16x32_f16(as_h8(au), Bp, O[nt], 0, 0, 0);
            }
        }

        #pragma unroll
        for (int reg = 0; reg < 4; ++reg) {
            float ss = 0.f;
            #pragma unroll
            for (int nt = 0; nt < 4; ++nt) ss = fmaf(O[nt][reg], O[nt][reg], ss);
            ss += __shfl_xor(ss, 1); ss += __shfl_xor(ss, 2);
            ss += __shfl_xor(ss, 4); ss += __shfl_xor(ss, 8);
            float invn = 1.f / fmaxf(sqrtf(ss), EPSF);
            int n = n0 + wv * 16 + q * 4 + reg;
            bool valid = n < count;
            size_t g = (size_t)(bse + n);
            #pragma unroll
            for (int nt = 0; nt < 4; ++nt) {
                float v  = O[nt][reg];
                float v1 = __shfl_xor(v, 1);
                float v2 = __shfl_xor(v, 2);
                float v3 = __shfl_xor(v, 3);
                if (valid) {
                    if (!(c & 1))
                        intl_h[g * 32 + ((nt * 16 + c) >> 1)] = pkrtz(v, v1);
                    if (!(c & 3))
                        pk[g * ROWD + 2 * ((nt * 16 + c) >> 2) + 1] =
                            enc8(v * invn, v1 * invn, v2 * invn, v3 * invn);
                }
            }
        }
    } else {
        // ===== gnn path: persistent waves, 8x8 groups, 2-stage pipeline =======
        int lane = tid & 63;
        int grp = lane >> 3, l8 = lane & 7;   // lane owns dims 8*l8 .. 8*l8+7
        int nw = GB * 4;
        for (int wid = (bid - NINT) * 4 + (tid >> 6); wid < NN; wid += nw) {
            int2 rd = rodeg[wid];
            int s = rd.x, eend = rd.x + rd.y;
            float a0 = 0.f, a1 = 0.f, a2 = 0.f, a3 = 0.f;
            float a4 = 0.f, a5 = 0.f, a6 = 0.f, a7 = 0.f;
            int e = s;
            int2 c  = csr[min(s + grp, eend - 1)];
            uint4 w = *(const uint4*)&pk[(size_t)c.x * ROWD + 32 + 4 * l8];
            int2 c1 = csr[min(s + 8 + grp, eend - 1)];
            for (; e + 7 < eend; e += 8) {
                int2 c2  = csr[min(e + 16 + grp, eend - 1)];
                uint4 w1 = *(const uint4*)&pk[(size_t)c1.x * ROWD + 32 + 4 * l8];
                float gv = __int_as_float(c.y);
                h2 x0 = as_h2(w.x), x1 = as_h2(w.y), x2 = as_h2(w.z), x3 = as_h2(w.w);
                a0 = fmaf(gv, (float)x0.x, a0); a1 = fmaf(gv, (float)x0.y, a1);
                a2 = fmaf(gv, (float)x1.x, a2); a3 = fmaf(gv, (float)x1.y, a3);
                a4 = fmaf(gv, (float)x2.x, a4); a5 = fmaf(gv, (float)x2.y, a5);
                a6 = fmaf(gv, (float)x3.x, a6); a7 = fmaf(gv, (float)x3.y, a7);
                c = c1; c1 = c2; w = w1;
            }
            if (e < eend) {
                bool val = e + grp < eend;
                float gv = val ? __int_as_float(c.y) : 0.f;
                h2 x0 = as_h2(w.x), x1 = as_h2(w.y), x2 = as_h2(w.z), x3 = as_h2(w.w);
                a0 = fmaf(gv, (float)x0.x, a0); a1 = fmaf(gv, (float)x0.y, a1);
                a2 = fmaf(gv, (float)x1.x, a2); a3 = fmaf(gv, (float)x1.y, a3);
                a4 = fmaf(gv, (float)x2.x, a4); a5 = fmaf(gv, (float)x2.y, a5);
                a6 = fmaf(gv, (float)x3.x, a6); a7 = fmaf(gv, (float)x3.y, a7);
            }
            #pragma unroll
            for (int m = 8; m <= 32; m <<= 1) {
                a0 += __shfl_xor(a0, m); a1 += __shfl_xor(a1, m);
                a2 += __shfl_xor(a2, m); a3 += __shfl_xor(a3, m);
                a4 += __shfl_xor(a4, m); a5 += __shfl_xor(a5, m);
                a6 += __shfl_xor(a6, m); a7 += __shfl_xor(a7, m);
            }
            float ss = fmaf(a0, a0, fmaf(a1, a1, fmaf(a2, a2, a3 * a3)))
                     + fmaf(a4, a4, fmaf(a5, a5, fmaf(a6, a6, a7 * a7)));
            ss += __shfl_xor(ss, 1); ss += __shfl_xor(ss, 2); ss += __shfl_xor(ss, 4);
            float inv = 1.f / fmaxf(sqrtf(ss), EPSF);
            if (grp == 0) {
                unsigned* pr = pk + (size_t)wid * ROWD;
                pr[4 * l8]     = enc8(a0 * inv, a1 * inv, a2 * inv, a3 * inv);
                pr[4 * l8 + 2] = enc8(a4 * inv, a5 * inv, a6 * inv, a7 * inv);
                uint4 xw = *(const uint4*)&pr[32 + 4 * l8];
                h2 x0 = as_h2(xw.x), x1 = as_h2(xw.y), x2 = as_h2(xw.z), x3 = as_h2(xw.w);
                *(uint4*)&base16[(size_t)wid * 32 + 4 * l8] = make_uint4(
                    pkrtz(a0 + (float)x0.x, a1 + (float)x0.y),
                    pkrtz(a2 + (float)x1.x, a3 + (float)x1.y),
                    pkrtz(a4 + (float)x2.x, a5 + (float)x2.y),
                    pkrtz(a6 + (float)x3.x, a7 + (float)x3.y));
            }
        }
    }
}

// ---------------- k_fused: persistent waves; 2-stage pipelined edge loop -----
// wave = 4 groups x 16 lanes; group g handles edges e+g / e+4+g
__global__ __launch_bounds__(256) void k_fused(const int2* __restrict__ rodeg,
                                               const int2* __restrict__ csr,
                                               const unsigned* __restrict__ pk,
                                               const unsigned* __restrict__ intl_h,
                                               const unsigned* __restrict__ base16,
                                               unsigned* __restrict__ pknext,
                                               float* __restrict__ acc) {
    int lane = threadIdx.x & 63;
    int grp = lane >> 4, l16 = lane & 15;
    int nw = GB * 4;
    for (int wid = blockIdx.x * 4 + (threadIdx.x >> 6); wid < NN; wid += nw) {
        const unsigned* ph = pk + (size_t)wid * ROWD;
        uint2 hq = *(const uint2*)&ph[2 * l16];
        f2 hgl = dec8lo(hq.x), hgh = dec8hi(hq.x);
        f2 hil = dec8lo(hq.y), hih = dec8hi(hq.y);

        int2 rd = rodeg[wid];
        int s = rd.x, eend = rd.x + rd.y;
        float sg = 0.f, si = 0.f;
        float g0 = 0.f, g1 = 0.f, g2 = 0.f, g3 = 0.f;
        float i0 = 0.f, i1 = 0.f, i2 = 0.f, i3 = 0.f;

        int e = s;
        int tA = csr[min(s + grp, eend - 1)].x;
        int tB = csr[min(s + 4 + grp, eend - 1)].x;
        const unsigned* pA = pk + (size_t)tA * ROWD;
        const unsigned* pB = pk + (size_t)tB * ROWD;
        uint2 qA = *(const uint2*)&pA[2 * l16];
        uint2 wA = *(const uint2*)&pA[32 + 2 * l16];
        uint2 qB = *(const uint2*)&pB[2 * l16];
        uint2 wB = *(const uint2*)&pB[32 + 2 * l16];
        int tA1 = csr[min(s + 8 + grp, eend - 1)].x;
        int tB1 = csr[min(s + 12 + grp, eend - 1)].x;

        for (; e + 7 < eend; e += 8) {
            int tA2 = csr[min(e + 16 + grp, eend - 1)].x;
            int tB2 = csr[min(e + 20 + grp, eend - 1)].x;
            const unsigned* pA1 = pk + (size_t)tA1 * ROWD;
            const unsigned* pB1 = pk + (size_t)tB1 * ROWD;
            uint2 qA1 = *(const uint2*)&pA1[2 * l16];
            uint2 wA1 = *(const uint2*)&pA1[32 + 2 * l16];
            uint2 qB1 = *(const uint2*)&pB1[2 * l16];
            uint2 wB1 = *(const uint2*)&pB1[32 + 2 * l16];
            f2 gA01 = dec8lo(qA.x), gA23 = dec8hi(qA.x);
            f2 iA01 = dec8lo(qA.y), iA23 = dec8hi(qA.y);
            f2 gB01 = dec8lo(qB.x), gB23 = dec8hi(qB.x);
            f2 iB01 = dec8lo(qB.y), iB23 = dec8hi(qB.y);
            float pgA = fmaf(hgl.x, gA01.x, fmaf(hgl.y, gA01.y,
                        fmaf(hgh.x, gA23.x, hgh.y * gA23.y)));
            float piA = fmaf(hil.x, iA01.x, fmaf(hil.y, iA01.y,
                        fmaf(hih.x, iA23.x, hih.y * iA23.y)));
            float pgB = fmaf(hgl.x, gB01.x, fmaf(hgl.y, gB01.y,
                        fmaf(hgh.x, gB23.x, hgh.y * gB23.y)));
            float piB = fmaf(hil.x, iB01.x, fmaf(hil.y, iB01.y,
                        fmaf(hih.x, iB23.x, hih.y * iB23.y)));
            #pragma unroll
            for (int m = 1; m <= 8; m <<= 1) {
                pgA += __shfl_xor(pgA, m); piA += __shfl_xor(piA, m);
                pgB += __shfl_xor(pgB, m); piB += __shfl_xor(piB, m);
            }
            float agA = fmaf(pgA, 0.5f, 0.5f), aiA = fmaf(piA, 0.5f, 0.5f);
            float agB = fmaf(pgB, 0.5f, 0.5f), aiB = fmaf(piB, 0.5f, 0.5f);
            sg += agA + agB; si += aiA + aiB;
            h2 xa0 = as_h2(wA.x), xa1 = as_h2(wA.y);
            h2 xb0 = as_h2(wB.x), xb1 = as_h2(wB.y);
            g0 = fmaf(agA, (float)xa0.x, g0); g1 = fmaf(agA, (float)xa0.y, g1);
            g2 = fmaf(agA, (float)xa1.x, g2); g3 = fmaf(agA, (float)xa1.y, g3);
            i0 = fmaf(aiA, (float)xa0.x, i0); i1 = fmaf(aiA, (float)xa0.y, i1);
            i2 = fmaf(aiA, (float)xa1.x, i2); i3 = fmaf(aiA, (float)xa1.y, i3);
            g0 = fmaf(agB, (float)xb0.x, g0); g1 = fmaf(agB, (float)xb0.y, g1);
            g2 = fmaf(agB, (float)xb1.x, g2); g3 = fmaf(agB, (float)xb1.y, g3);
            i0 = fmaf(aiB, (float)xb0.x, i0); i1 = fmaf(aiB, (float)xb0.y, i1);
            i2 = fmaf(aiB, (float)xb1.x, i2); i3 = fmaf(aiB, (float)xb1.y, i3);
            tA1 = tA2; tB1 = tB2;
            qA = qA1; wA = wA1; qB = qB1; wB = wB1;
        }
        if (e < eend) {
            bool val = e + grp < eend;
            f2 tg01 = dec8lo(qA.x), tg23 = dec8hi(qA.x);
            f2 ti01 = dec8lo(qA.y), ti23 = dec8hi(qA.y);
            float pg = fmaf(hgl.x, tg01.x, fmaf(hgl.y, tg01.y,
                       fmaf(hgh.x, tg23.x, hgh.y * tg23.y)));
            float pi = fmaf(hil.x, ti01.x, fmaf(hil.y, ti01.y,
                       fmaf(hih.x, ti23.x, hih.y * ti23.y)));
            #pragma unroll
            for (int m = 1; m <= 8; m <<= 1) {
                pg += __shfl_xor(pg, m); pi += __shfl_xor(pi, m);
            }
            float ag = fmaf(pg, 0.5f, 0.5f), ai = fmaf(pi, 0.5f, 0.5f);
            if (!val) { ag = 0.f; ai = 0.f; }
            sg += ag; si += ai;
            h2 x0 = as_h2(wA.x), x1 = as_h2(wA.y);
            g0 = fmaf(ag, (float)x0.x, g0); g1 = fmaf(ag, (float)x0.y, g1);
            g2 = fmaf(ag, (float)x1.x, g2); g3 = fmaf(ag, (float)x1.y, g3);
            i0 = fmaf(ai, (float)x0.x, i0); i1 = fmaf(ai, (float)x0.y, i1);
            i2 = fmaf(ai, (float)x1.x, i2); i3 = fmaf(ai, (float)x1.y, i3);
        }
        if (e + 4 < eend) {
            bool val = e + 4 + grp < eend;
            f2 tg01 = dec8lo(qB.x), tg23 = dec8hi(qB.x);
            f2 ti01 = dec8lo(qB.y), ti23 = dec8hi(qB.y);
            float pg = fmaf(hgl.x, tg01.x, fmaf(hgl.y, tg01.y,
                       fmaf(hgh.x, tg23.x, hgh.y * tg23.y)));
            float pi = fmaf(hil.x, ti01.x, fmaf(hil.y, ti01.y,
                       fmaf(hih.x, ti23.x, hih.y * ti23.y)));
            #pragma unroll
            for (int m = 1; m <= 8; m <<= 1) {
                pg += __shfl_xor(pg, m); pi += __shfl_xor(pi, m);
            }
            float ag = fmaf(pg, 0.5f, 0.5f), ai = fmaf(pi, 0.5f, 0.5f);
            if (!val) { ag = 0.f; ai = 0.f; }
            sg += ag; si += ai;
            h2 x0 = as_h2(wB.x), x1 = as_h2(wB.y);
            g0 = fmaf(ag, (float)x0.x, g0); g1 = fmaf(ag, (float)x0.y, g1);
            g2 = fmaf(ag, (float)x1.x, g2); g3 = fmaf(ag, (float)x1.y, g3);
            i0 = fmaf(ai, (float)x0.x, i0); i1 = fmaf(ai, (float)x0.y, i1);
            i2 = fmaf(ai, (float)x1.x, i2); i3 = fmaf(ai, (float)x1.y, i3);
        }

        #pragma unroll
        for (int m = 16; m <= 32; m <<= 1) {
            sg += __shfl_xor(sg, m); si += __shfl_xor(si, m);
            g0 += __shfl_xor(g0, m); g1 += __shfl_xor(g1, m);
            g2 += __shfl_xor(g2, m); g3 += __shfl_xor(g3, m);
            i0 += __shfl_xor(i0, m); i1 += __shfl_xor(i1, m);
            i2 += __shfl_xor(i2, m); i3 += __shfl_xor(i3, m);
        }

        if (grp == 0) {
            float invg = sg > 0.f ? 1.f / sg : 0.f;
            float invi = si > 0.f ? 1.f / si : 0.f;
            size_t bidx = (size_t)wid * 16 + l16;
            uint2 bw = *(const uint2*)&base16[(size_t)wid * 32 + 2 * l16];
            h2 b0 = as_h2(bw.x), b1 = as_h2(bw.y);
            uint2 iw = *(const uint2*)&intl_h[(size_t)wid * 32 + 2 * l16];
            h2 il0 = as_h2(iw.x), il1 = as_h2(iw.y);
            float o0 = (float)b0.x + (float)il0.x + invg * g0 + invi * i0;
            float o1 = (float)b0.y + (float)il0.y + invg * g1 + invi * i1;
            float o2 = (float)b1.x + (float)il1.x + invg * g2 + invi * i2;
            float o3 = (float)b1.y + (float)il1.y + invg * g3 + invi * i3;
            *(uint2*)&pknext[(size_t)wid * ROWD + 32 + 2 * l16] =
                make_uint2(pkrtz(o0, o1), pkrtz(o2, o3));
            float4 a = ((float4*)acc)[bidx];
            a.x += o0; a.y += o1; a.z += o2; a.w += o3;
            ((float4*)acc)[bidx] = a;
        }
    }
}

// ---------------- launch ----------------

extern "C" void kernel_launch(void* const* d_in, const int* in_sizes, int n_in,
                              void* d_out, int out_size, void* d_ws, size_t ws_size,
                              hipStream_t stream) {
    const float* emb   = (const float*)d_in[0];
    const float* Wu    = (const float*)d_in[1];
    const float* Wi    = (const float*)d_in[2];
    const int*   all_h = (const int*)d_in[3];
    const int*   all_t = (const int*)d_in[4];
    float*       acc   = (float*)d_out;

    char*  bp  = (char*)d_ws;
    size_t off = 0;
    auto take = [&](size_t bytes) -> char* {
        char* r = bp + off;
        off = (off + bytes + 255) & ~(size_t)255;
        return r;
    };
    int*      deg     = (int*)     take((size_t)NN * 4);
    int*      row_off = (int*)     take((size_t)NN * 4);
    int2*     rodeg   = (int2*)    take((size_t)NN * 8);
    int*      row_cur = (int*)     take((size_t)NN * 4);
    int*      counter = (int*)     take(256);
    float*    d_inv   = (float*)   take((size_t)NN * 4);
    int2*     csr     = (int2*)    take((size_t)NE * 8);
    unsigned* pkA     = (unsigned*)take((size_t)NN * ROWD * 4);
    unsigned* pkB     = (unsigned*)take((size_t)NN * ROWD * 4);
    unsigned* intl_h  = (unsigned*)take((size_t)NN * 32 * 4);
    unsigned* base16  = (unsigned*)take((size_t)NN * 32 * 4);
    uint4*    WfA     = (uint4*)   take((size_t)2048 * 16);
    uint4*    Wf2     = (uint4*)   take((size_t)2048 * 16);
    (void)ws_size; (void)in_sizes; (void)n_in; (void)out_size;

    hipMemsetAsync(deg, 0, (size_t)NN * 4, stream);
    hipMemsetAsync(row_cur, 0, (size_t)NN * 4, stream);
    hipMemsetAsync(counter, 0, 256, stream);

    const int NBK = (NN + 255) / 256;
    k_pre<<<PREG, 256, 0, stream>>>(all_h, deg, emb, acc, pkA, Wu, Wi, WfA, Wf2);
    k_rowoff<<<NBK, 256, 0, stream>>>(deg, counter, row_off, rodeg, d_inv);
    k_scatter<<<EB, 256, 0, stream>>>(all_h, all_t, row_off, row_cur, d_inv, csr);

    unsigned* cur = pkA;
    unsigned* nxt = pkB;
    for (int l = 0; l < 3; ++l) {
        k_mid<<<NINT + GB, 256, 0, stream>>>(rodeg, csr, cur, intl_h,
                                             WfA, Wf2, base16);
        k_fused<<<GB, 256, 0, stream>>>(rodeg, csr, cur, intl_h,
                                        base16, nxt, acc);
        unsigned* tmp = cur; cur = nxt; nxt = tmp;
    }
}